// Round 4
// baseline (124.021 us; speedup 1.0000x reference)
//
#include <hip/hip_runtime.h>
#include <hip/hip_bf16.h>

typedef float f32x4 __attribute__((ext_vector_type(4)));
typedef __bf16 bf16x8 __attribute__((ext_vector_type(8)));

static constexpr int BB = 32;      // batch
static constexpr int DM = 2560;    // d_model
static constexpr int DI = 5120;    // d_inner
static constexpr int NS = 16;      // ssm state N
static constexpr int RK = 160;     // dt_rank
static constexpr int NJ = 192;     // dt_rank + 2N

__device__ __forceinline__ float sigmoidf_(float x) { return 1.f / (1.f + __expf(-x)); }
__device__ __forceinline__ float softplusf_(float x) {
    return (x > 15.f) ? x : log1pf(__expf(x));
}

__device__ __forceinline__ bf16x8 cvt8(f32x4 a, f32x4 b) {
    bf16x8 r;
    r[0] = (__bf16)a[0]; r[1] = (__bf16)a[1]; r[2] = (__bf16)a[2]; r[3] = (__bf16)a[3];
    r[4] = (__bf16)b[0]; r[5] = (__bf16)b[1]; r[6] = (__bf16)b[2]; r[7] = (__bf16)b[3];
    return r;
}

// Opaque (un-sinkable) 16B global load: compiler cannot move/merge/sink it.
#define GLD(dst, ptr, OFF) \
    asm volatile("global_load_dwordx4 %0, %1, off offset:" OFF \
                 : "=v"(dst) : "v"(ptr) : "memory")

// Load one 64-k fragment tile (W and X, 8 consecutive floats per lane at kc
// and kc+32): 8 loads, 128B total per lane pair-group.
#define LOADT(w0, w1, w2, w3, x0, x1, x2, x3, wp, xp) \
    do {                                              \
        GLD(w0, wp, "0");   GLD(w1, wp, "16");        \
        GLD(w2, wp, "128"); GLD(w3, wp, "144");       \
        GLD(x0, xp, "0");   GLD(x1, xp, "16");        \
        GLD(x2, xp, "128"); GLD(x3, xp, "144");       \
    } while (0)

#define WAITN(N) do { \
        asm volatile("s_waitcnt vmcnt(" #N ")" ::: "memory"); \
        __builtin_amdgcn_sched_barrier(0); \
    } while (0)

// ---------------------------------------------------------------------------
// Skinny GEMM, register-pipelined: C[s][b][d] = sum_{k in slice s} W[d,k]X[b,k].
// Per block: 32 d x 32 b tile, 4 waves each computing a 16x16 quadrant.
// Two register tile-buffers (A/B), 8 asm loads each, steady-state 16 loads in
// flight per wave, counted vmcnt(8) waits. NO LDS, NO barriers, NO atomics:
// split-K slices write disjoint partial buffers (C + s*cstride), reduced by
// the consumer. ksteps must be even and >= 2.
// ---------------------------------------------------------------------------
__global__ __launch_bounds__(256) void gemm32(
    const float* __restrict__ W0, float* __restrict__ C0,
    const float* __restrict__ W1, float* __restrict__ C1,
    const float* __restrict__ X,
    int K, int ldc, int nm, int S, int ksteps, int cstride)
{
    int bid = blockIdx.x;
    int m = bid % nm;
    int rest = bid / nm;
    int s = rest % S;
    int mat = rest / S;
    const float* W = mat ? W1 : W0;
    float* C = (mat ? C1 : C0) + (size_t)s * cstride;

    int d0 = m * 32;
    int k0 = s * (K / S);

    int t  = threadIdx.x;
    int l  = t & 63;
    int wv = t >> 6;            // wave 0..3
    int mh = wv & 1;            // d-half of 32x32 tile
    int nh = wv >> 1;           // batch-half
    int r16 = l & 15;
    int kc  = (l >> 4) * 8;     // 0,8,16,24

    const float* wpA = W + (size_t)(d0 + mh * 16 + r16) * K + k0 + kc;
    const float* xpA = X + (size_t)(nh * 16 + r16) * K + k0 + kc;
    const float* wpB = wpA + 64;
    const float* xpB = xpA + 64;

    f32x4 Aw0, Aw1, Aw2, Aw3, Ax0, Ax1, Ax2, Ax3;
    f32x4 Bw0, Bw1, Bw2, Bw3, Bx0, Bx1, Bx2, Bx3;

    LOADT(Aw0, Aw1, Aw2, Aw3, Ax0, Ax1, Ax2, Ax3, wpA, xpA);
    wpA += 128; xpA += 128;
    LOADT(Bw0, Bw1, Bw2, Bw3, Bx0, Bx1, Bx2, Bx3, wpB, xpB);
    wpB += 128; xpB += 128;

    f32x4 acc = {0.f, 0.f, 0.f, 0.f};

    for (int it = 0; it < (ksteps - 2) / 2; ++it) {
        WAITN(8);   // tile A's 8 loads complete; B's 8 still in flight
        acc = __builtin_amdgcn_mfma_f32_16x16x32_bf16(cvt8(Aw0, Aw1), cvt8(Ax0, Ax1), acc, 0, 0, 0);
        acc = __builtin_amdgcn_mfma_f32_16x16x32_bf16(cvt8(Aw2, Aw3), cvt8(Ax2, Ax3), acc, 0, 0, 0);
        LOADT(Aw0, Aw1, Aw2, Aw3, Ax0, Ax1, Ax2, Ax3, wpA, xpA);
        wpA += 128; xpA += 128;
        WAITN(8);   // tile B done; new A in flight
        acc = __builtin_amdgcn_mfma_f32_16x16x32_bf16(cvt8(Bw0, Bw1), cvt8(Bx0, Bx1), acc, 0, 0, 0);
        acc = __builtin_amdgcn_mfma_f32_16x16x32_bf16(cvt8(Bw2, Bw3), cvt8(Bx2, Bx3), acc, 0, 0, 0);
        LOADT(Bw0, Bw1, Bw2, Bw3, Bx0, Bx1, Bx2, Bx3, wpB, xpB);
        wpB += 128; xpB += 128;
    }
    WAITN(8);
    acc = __builtin_amdgcn_mfma_f32_16x16x32_bf16(cvt8(Aw0, Aw1), cvt8(Ax0, Ax1), acc, 0, 0, 0);
    acc = __builtin_amdgcn_mfma_f32_16x16x32_bf16(cvt8(Aw2, Aw3), cvt8(Ax2, Ax3), acc, 0, 0, 0);
    WAITN(0);
    acc = __builtin_amdgcn_mfma_f32_16x16x32_bf16(cvt8(Bw0, Bw1), cvt8(Bx0, Bx1), acc, 0, 0, 0);
    acc = __builtin_amdgcn_mfma_f32_16x16x32_bf16(cvt8(Bw2, Bw3), cvt8(Bx2, Bx3), acc, 0, 0, 0);

    // C/D layout: col(batch) = l&15, row(d) = (l>>4)*4 + j -> 16B store per lane
    int b = nh * 16 + r16;
    int dbase = d0 + mh * 16 + (l >> 4) * 4;
    *(f32x4*)&C[(size_t)b * ldc + dbase] = acc;
}

// ---------------------------------------------------------------------------
// Depthwise causal conv (k=4) + SiLU.  Also reduces the K1 split-K partials:
// xs = Pxs[0]+Pxs[1], res_bd = Pres[0]+Pres[1].
// ---------------------------------------------------------------------------
__global__ __launch_bounds__(256) void convk(
    const float* __restrict__ P_xs, const float* __restrict__ P_res,
    const float* __restrict__ conv_states,
    const float* __restrict__ conv_w, const float* __restrict__ conv_b,
    float* __restrict__ conv_bd, float* __restrict__ res_bd)
{
    const size_t BD = (size_t)BB * DI;
    int d = blockIdx.x * 256 + threadIdx.x;
    int b = blockIdx.y;
    size_t o = (size_t)b * DI + d;
    float xs = P_xs[o] + P_xs[BD + o];
    res_bd[o] = P_res[o] + P_res[BD + o];
    float v = conv_states[(size_t)(1 * BB + b) * DI + d] * conv_w[0 * DI + d]
            + conv_states[(size_t)(2 * BB + b) * DI + d] * conv_w[1 * DI + d]
            + conv_states[(size_t)(3 * BB + b) * DI + d] * conv_w[2 * DI + d]
            + xs * conv_w[3 * DI + d] + conv_b[d];
    conv_bd[o] = v * sigmoidf_(v);
}

// ---------------------------------------------------------------------------
// Reduce K2 split-K partials: x_db[i] = sum_s x_db_p[s][i],  i < BB*NJ = 6144.
// ---------------------------------------------------------------------------
__global__ __launch_bounds__(256) void redx(
    const float* __restrict__ p, float* __restrict__ o, int S)
{
    int i = blockIdx.x * 256 + threadIdx.x;
    float sum = 0.f;
    for (int s = 0; s < S; ++s) sum += p[(size_t)s * BB * NJ + i];
    o[i] = sum;
}

// ---------------------------------------------------------------------------
// Reduce K4 split-K partials into d_out: out[i] = sum_{s<4} p[s][i].
// ---------------------------------------------------------------------------
__global__ __launch_bounds__(256) void rout(
    const float* __restrict__ p, float* __restrict__ o)
{
    const int SZ = BB * DM;
    int i = blockIdx.x * 256 + threadIdx.x;
    o[i] = p[i] + p[SZ + i] + p[2 * SZ + i] + p[3 * SZ + i];
}

// ---------------------------------------------------------------------------
// dt GEMV: dt[b][d] = softplus(x_db[b,0:160] @ W_dt[d,:] + dt_bias[d]).
// ---------------------------------------------------------------------------
__global__ __launch_bounds__(256) void dtk(
    const float* __restrict__ x_db, const float* __restrict__ W_dt,
    const float* __restrict__ dt_bias, float* __restrict__ dt_bd)
{
    __shared__ float Wdt_s[8][164];
    __shared__ float xdb_s[BB][164];

    int t = threadIdx.x;
    int d0 = blockIdx.x * 8;

    for (int f = t; f < 8 * RK; f += 256) {
        Wdt_s[f / RK][f % RK] = W_dt[(size_t)d0 * RK + f];
    }
    for (int f = t; f < BB * RK; f += 256) {
        int b = f / RK, k = f % RK;
        xdb_s[b][k] = x_db[(size_t)b * NJ + k];
    }
    __syncthreads();

    int b  = t & 31;
    int dl = t >> 5;

    float acc = 0.f;
    #pragma unroll 8
    for (int k4 = 0; k4 < RK / 4; ++k4) {
        f32x4 wv = *(const f32x4*)&Wdt_s[dl][k4 * 4];
        f32x4 xv = *(const f32x4*)&xdb_s[b][k4 * 4];
        acc += wv[0] * xv[0] + wv[1] * xv[1] + wv[2] * xv[2] + wv[3] * xv[3];
    }

    int d = d0 + dl;
    dt_bd[(size_t)b * DI + d] = softplusf_(acc + dt_bias[d]);
}

// ---------------------------------------------------------------------------
// SSM recurrence + D skip + SiLU gate.  One thread per (b,d).
// ---------------------------------------------------------------------------
__global__ __launch_bounds__(256) void ssm2(
    const float* __restrict__ x_db, const float* __restrict__ dt_bd,
    const float* __restrict__ A_log, const float* __restrict__ Dv,
    const float* __restrict__ ssm_state, const float* __restrict__ conv_bd,
    const float* __restrict__ res_bd, float* __restrict__ g_bd)
{
    __shared__ float Bc[NS], Cc[NS];

    int t = threadIdx.x;
    int b = blockIdx.x / (DI / 256);
    int dblk = blockIdx.x % (DI / 256);
    int d = dblk * 256 + t;

    if (t < NS) Bc[t] = x_db[(size_t)b * NJ + RK + t];
    else if (t < 2 * NS) Cc[t - NS] = x_db[(size_t)b * NJ + RK + t];
    __syncthreads();

    size_t off = (size_t)b * DI + d;
    float dt = dt_bd[off];
    float cv = conv_bd[off];
    float rv = res_bd[off];
    float Dd = Dv[d];

    const f32x4* ap = (const f32x4*)(A_log + (size_t)d * NS);
    const f32x4* sp = (const f32x4*)(ssm_state + off * NS);

    float y = 0.f;
    #pragma unroll
    for (int q = 0; q < 4; ++q) {
        f32x4 al = ap[q];
        f32x4 sv = sp[q];
        #pragma unroll
        for (int j = 0; j < 4; ++j) {
            int n = q * 4 + j;
            float dA = __expf(-dt * __expf(al[j]));
            y += (sv[j] * dA + dt * Bc[n] * cv) * Cc[n];
        }
    }
    y += Dd * cv;
    g_bd[off] = y * (rv * sigmoidf_(rv));
}

// ---------------------------------------------------------------------------

extern "C" void kernel_launch(void* const* d_in, const int* in_sizes, int n_in,
                              void* d_out, int out_size, void* d_ws, size_t ws_size,
                              hipStream_t stream)
{
    const float* x           = (const float*)d_in[0];
    const float* conv_states = (const float*)d_in[1];
    const float* conv_w      = (const float*)d_in[2];
    const float* conv_b      = (const float*)d_in[3];
    const float* W_ssm_in    = (const float*)d_in[4];
    const float* W_mlp       = (const float*)d_in[5];
    const float* W_out       = (const float*)d_in[6];
    const float* W_x_proj    = (const float*)d_in[7];
    const float* W_dt        = (const float*)d_in[8];
    const float* dt_bias     = (const float*)d_in[9];
    const float* A_log       = (const float*)d_in[10];
    const float* Dv          = (const float*)d_in[11];
    const float* ssm_state   = (const float*)d_in[12];

    float* out = (float*)d_out;
    float* ws  = (float*)d_ws;

    const size_t BD = (size_t)BB * DI;         // 163840
    const int S2 = 20;                          // K2 split
    float* P_res   = ws;                        // 2*BD (K1 partials) -> later g_bd
    float* P_xs    = ws + 2 * BD;               // 2*BD (K1 partials) -> later outp
    float* conv_bd = ws + 4 * BD;
    float* res_bd  = ws + 5 * BD;
    float* dt_bd   = ws + 6 * BD;
    float* x_db_p  = ws + 7 * BD;               // S2 * 6144
    float* x_db    = ws + 7 * BD + (size_t)S2 * BB * NJ;
    float* g_bd    = ws;                        // alias (P_res dead after convk)
    float* outp    = ws + 2 * BD;               // alias (P_xs dead after convk), 4*BB*DM = 2*BD

    // K1: res/xs partials (dual matrix, split-K 2): K=2560, ksteps=20
    gemm32<<<dim3(160 * 2 * 2), 256, 0, stream>>>(
        W_mlp, P_res, W_ssm_in, P_xs, x, DM, DI, 160, 2, 20, (int)BD);

    // conv + silu + reduce K1 partials
    convk<<<dim3(DI / 256, BB), 256, 0, stream>>>(
        P_xs, P_res, conv_states, conv_w, conv_b, conv_bd, res_bd);

    // K2: x_db partials = conv @ W_x_proj.T  (K=5120, split-K 20, ksteps=4)
    gemm32<<<dim3(6 * S2), 256, 0, stream>>>(
        W_x_proj, x_db_p, W_x_proj, x_db_p, conv_bd, DI, NJ, 6, S2, 4, BB * NJ);

    // reduce x_db partials
    redx<<<dim3((BB * NJ) / 256), 256, 0, stream>>>(x_db_p, x_db, S2);

    // dt GEMV + softplus
    dtk<<<dim3(DI / 8), 256, 0, stream>>>(x_db, W_dt, dt_bias, dt_bd);

    // SSM recurrence + gate
    ssm2<<<dim3(BB * (DI / 256)), 256, 0, stream>>>(
        x_db, dt_bd, A_log, Dv, ssm_state, conv_bd, res_bd, g_bd);

    // K4: out partials = g @ W_out.T  (K=5120, split-K 4, ksteps=20)
    gemm32<<<dim3(80 * 4), 256, 0, stream>>>(
        W_out, outp, W_out, outp, g_bd, DI, DM, 80, 4, 20, BB * DM);

    // final reduce into d_out
    rout<<<dim3((BB * DM) / 256), 256, 0, stream>>>(outp, out);
}

// Round 5
// 64.374 us; speedup vs baseline: 1.9266x; 1.9266x over previous
//
#include <hip/hip_runtime.h>
#include <hip/hip_bf16.h>

typedef float f32x4 __attribute__((ext_vector_type(4)));
typedef __bf16 bf16x8 __attribute__((ext_vector_type(8)));

#define AS1 __attribute__((address_space(1)))
#define AS3 __attribute__((address_space(3)))

static constexpr int BB = 32;      // batch
static constexpr int DM = 2560;    // d_model
static constexpr int DI = 5120;    // d_inner
static constexpr int NS = 16;      // ssm state N
static constexpr int RK = 160;     // dt_rank
static constexpr int NJ = 192;     // dt_rank + 2N

__device__ __forceinline__ float sigmoidf_(float x) { return 1.f / (1.f + __expf(-x)); }
__device__ __forceinline__ float softplusf_(float x) {
    return (x > 15.f) ? x : log1pf(__expf(x));
}

__device__ __forceinline__ bf16x8 cvt8(f32x4 a, f32x4 b) {
    bf16x8 r;
    r[0] = (__bf16)a[0]; r[1] = (__bf16)a[1]; r[2] = (__bf16)a[2]; r[3] = (__bf16)a[3];
    r[4] = (__bf16)b[0]; r[5] = (__bf16)b[1]; r[6] = (__bf16)b[2]; r[7] = (__bf16)b[3];
    return r;
}

// Counted waits: loads stay in flight across raw barriers (T4). sched_barrier
// per rule #18 so nothing is hoisted above the wait.
#define WAIT4 do { asm volatile("s_waitcnt vmcnt(4)" ::: "memory"); \
                   __builtin_amdgcn_sched_barrier(0); } while (0)
#define WAIT0 do { asm volatile("s_waitcnt vmcnt(0)" ::: "memory"); \
                   __builtin_amdgcn_sched_barrier(0); } while (0)

// ---------------------------------------------------------------------------
// Skinny GEMM, LDS-staged via global_load_lds (wave-contiguous 1KB/instr):
// C[s][b][d] = sum_{k slice s} W[d,k] * X[b,k].  32 d x 32 b tile, BK=64.
// Double-buffered LDS (2 x (8KB W + 8KB X) = 32KB), counted vmcnt(4), raw
// s_barrier (no vmcnt0 drain). LDS holds tile XOR-swizzled: slot(row,c) has
// global chunk c^(row&7) -- achieved by pre-swizzling the per-lane GLOBAL
// source (LDS dest is lane-linear by HW). ds_read_b128 frag reads then hit
// 8 distinct bank-quads per 8 rows (2 lanes/bank = free).
// Split-K partials to disjoint buffers (no atomics); consumer reduces.
// ---------------------------------------------------------------------------
__global__ __launch_bounds__(256) void gemm32(
    const float* __restrict__ W0, float* __restrict__ C0,
    const float* __restrict__ W1, float* __restrict__ C1,
    const float* __restrict__ X,
    int K, int ldc, int nm, int S, int ksteps, int cstride)
{
    __shared__ float Wb[2][32 * 64];
    __shared__ float Xb[2][32 * 64];

    int bid = blockIdx.x;
    int m = bid % nm;
    int rest = bid / nm;
    int s = rest % S;
    int mat = rest / S;
    const float* W = mat ? W1 : W0;
    float* C = (mat ? C1 : C0) + (size_t)s * cstride;

    int d0 = m * 32;
    int k0 = s * (K / S);

    int t  = threadIdx.x;
    int l  = t & 63;
    int wv = t >> 6;            // wave 0..3
    int lr = l >> 4;            // 0..3 row within staging instr
    int lc = l & 15;            // 16B chunk slot within row

    // staging: wave wv covers rows 8wv..8wv+7 of both tiles (2 instr each)
    int row0 = 8 * wv + lr;     // instr 0 rows
    int row1 = row0 + 4;        // instr 1 rows
    int ch0 = lc ^ (row0 & 7);  // pre-swizzled global chunk
    int ch1 = lc ^ (row1 & 7);
    const float* ws0 = W + (size_t)(d0 + row0) * K + k0 + ch0 * 4;
    const float* ws1 = W + (size_t)(d0 + row1) * K + k0 + ch1 * 4;
    const float* xs0 = X + (size_t)row0 * K + k0 + ch0 * 4;
    const float* xs1 = X + (size_t)row1 * K + k0 + ch1 * 4;
    int R0 = 8 * wv * 64;            // wave-uniform LDS float offsets
    int R1 = (8 * wv + 4) * 64;

#define STAGE(pb)  do {                                                              \
        __builtin_amdgcn_global_load_lds((const AS1 void*)ws0, (AS3 void*)&Wb[pb][R0], 16, 0, 0); \
        __builtin_amdgcn_global_load_lds((const AS1 void*)ws1, (AS3 void*)&Wb[pb][R1], 16, 0, 0); \
        __builtin_amdgcn_global_load_lds((const AS1 void*)xs0, (AS3 void*)&Xb[pb][R0], 16, 0, 0); \
        __builtin_amdgcn_global_load_lds((const AS1 void*)xs1, (AS3 void*)&Xb[pb][R1], 16, 0, 0); \
        ws0 += 64; ws1 += 64; xs0 += 64; xs1 += 64;                                  \
    } while (0)

    // fragment read offsets (loop-invariant): lane l -> W row arow, X row brow,
    // chunks c0,c0+1 (k 0..7 of frag) and c0+8,c0+9 (k 32..39), XOR-unswizzled.
    int mh = wv & 1, nh = wv >> 1;
    int r16 = l & 15;
    int arow = mh * 16 + r16;
    int brow = nh * 16 + r16;
    int c0 = (l >> 4) * 2;
    int wo0 = arow * 64 + ((c0    ) ^ (arow & 7)) * 4;
    int wo1 = arow * 64 + ((c0 + 1) ^ (arow & 7)) * 4;
    int wo2 = arow * 64 + ((c0 + 8) ^ (arow & 7)) * 4;
    int wo3 = arow * 64 + ((c0 + 9) ^ (arow & 7)) * 4;
    int xo0 = brow * 64 + ((c0    ) ^ (brow & 7)) * 4;
    int xo1 = brow * 64 + ((c0 + 1) ^ (brow & 7)) * 4;
    int xo2 = brow * 64 + ((c0 + 8) ^ (brow & 7)) * 4;
    int xo3 = brow * 64 + ((c0 + 9) ^ (brow & 7)) * 4;

    STAGE(0);
    STAGE(1);

    f32x4 acc = {0.f, 0.f, 0.f, 0.f};

    for (int it = 0; it < ksteps; ++it) {
        int c = it & 1;
        if (it < ksteps - 1) WAIT4; else WAIT0;   // my stage for buf c complete
        __builtin_amdgcn_s_barrier();             // everyone's stage complete

        f32x4 a0 = *(const f32x4*)&Wb[c][wo0];
        f32x4 a1 = *(const f32x4*)&Wb[c][wo1];
        f32x4 a2 = *(const f32x4*)&Wb[c][wo2];
        f32x4 a3 = *(const f32x4*)&Wb[c][wo3];
        f32x4 b0 = *(const f32x4*)&Xb[c][xo0];
        f32x4 b1 = *(const f32x4*)&Xb[c][xo1];
        f32x4 b2 = *(const f32x4*)&Xb[c][xo2];
        f32x4 b3 = *(const f32x4*)&Xb[c][xo3];
        acc = __builtin_amdgcn_mfma_f32_16x16x32_bf16(cvt8(a0, a1), cvt8(b0, b1), acc, 0, 0, 0);
        acc = __builtin_amdgcn_mfma_f32_16x16x32_bf16(cvt8(a2, a3), cvt8(b2, b3), acc, 0, 0, 0);

        __builtin_amdgcn_s_barrier();             // all waves done reading buf c
        if (it + 2 < ksteps) STAGE(c);            // overwrite c for k-step it+2
    }
#undef STAGE

    // C/D layout: col(batch) = l&15, row(d) = (l>>4)*4 + j -> 16B store
    int b = brow;
    int dbase = d0 + mh * 16 + (l >> 4) * 4;
    *(f32x4*)&C[(size_t)b * ldc + dbase] = acc;
}

// ---------------------------------------------------------------------------
// Depthwise causal conv (k=4) + SiLU.  Also reduces K1 split-K partials (S=4).
// ---------------------------------------------------------------------------
__global__ __launch_bounds__(256) void convk(
    const float* __restrict__ P_xs, const float* __restrict__ P_res,
    const float* __restrict__ conv_states,
    const float* __restrict__ conv_w, const float* __restrict__ conv_b,
    float* __restrict__ conv_bd, float* __restrict__ res_bd)
{
    const size_t BD = (size_t)BB * DI;
    int d = blockIdx.x * 256 + threadIdx.x;
    int b = blockIdx.y;
    size_t o = (size_t)b * DI + d;
    float xs = P_xs[o] + P_xs[BD + o] + P_xs[2 * BD + o] + P_xs[3 * BD + o];
    res_bd[o] = P_res[o] + P_res[BD + o] + P_res[2 * BD + o] + P_res[3 * BD + o];
    float v = conv_states[(size_t)(1 * BB + b) * DI + d] * conv_w[0 * DI + d]
            + conv_states[(size_t)(2 * BB + b) * DI + d] * conv_w[1 * DI + d]
            + conv_states[(size_t)(3 * BB + b) * DI + d] * conv_w[2 * DI + d]
            + xs * conv_w[3 * DI + d] + conv_b[d];
    conv_bd[o] = v * sigmoidf_(v);
}

// ---------------------------------------------------------------------------
// Reduce K2 split-K partials: x_db[i] = sum_s x_db_p[s][i],  i < BB*NJ.
// ---------------------------------------------------------------------------
__global__ __launch_bounds__(256) void redx(
    const float* __restrict__ p, float* __restrict__ o, int S)
{
    int i = blockIdx.x * 256 + threadIdx.x;
    float sum = 0.f;
    for (int s = 0; s < S; ++s) sum += p[(size_t)s * BB * NJ + i];
    o[i] = sum;
}

// ---------------------------------------------------------------------------
// Reduce K4 split-K partials (S=8) into d_out.
// ---------------------------------------------------------------------------
__global__ __launch_bounds__(256) void rout(
    const float* __restrict__ p, float* __restrict__ o)
{
    const int SZ = BB * DM;
    int i = blockIdx.x * 256 + threadIdx.x;
    float s = 0.f;
    #pragma unroll
    for (int j = 0; j < 8; ++j) s += p[(size_t)j * SZ + i];
    o[i] = s;
}

// ---------------------------------------------------------------------------
// dt GEMV: dt[b][d] = softplus(x_db[b,0:160] @ W_dt[d,:] + dt_bias[d]).
// ---------------------------------------------------------------------------
__global__ __launch_bounds__(256) void dtk(
    const float* __restrict__ x_db, const float* __restrict__ W_dt,
    const float* __restrict__ dt_bias, float* __restrict__ dt_bd)
{
    __shared__ float Wdt_s[8][164];
    __shared__ float xdb_s[BB][164];

    int t = threadIdx.x;
    int d0 = blockIdx.x * 8;

    for (int f = t; f < 8 * RK; f += 256) {
        Wdt_s[f / RK][f % RK] = W_dt[(size_t)d0 * RK + f];
    }
    for (int f = t; f < BB * RK; f += 256) {
        int b = f / RK, k = f % RK;
        xdb_s[b][k] = x_db[(size_t)b * NJ + k];
    }
    __syncthreads();

    int b  = t & 31;
    int dl = t >> 5;

    float acc = 0.f;
    #pragma unroll 8
    for (int k4 = 0; k4 < RK / 4; ++k4) {
        f32x4 wv = *(const f32x4*)&Wdt_s[dl][k4 * 4];
        f32x4 xv = *(const f32x4*)&xdb_s[b][k4 * 4];
        acc += wv[0] * xv[0] + wv[1] * xv[1] + wv[2] * xv[2] + wv[3] * xv[3];
    }

    int d = d0 + dl;
    dt_bd[(size_t)b * DI + d] = softplusf_(acc + dt_bias[d]);
}

// ---------------------------------------------------------------------------
// SSM recurrence + D skip + SiLU gate.  One thread per (b,d).
// ---------------------------------------------------------------------------
__global__ __launch_bounds__(256) void ssm2(
    const float* __restrict__ x_db, const float* __restrict__ dt_bd,
    const float* __restrict__ A_log, const float* __restrict__ Dv,
    const float* __restrict__ ssm_state, const float* __restrict__ conv_bd,
    const float* __restrict__ res_bd, float* __restrict__ g_bd)
{
    __shared__ float Bc[NS], Cc[NS];

    int t = threadIdx.x;
    int b = blockIdx.x / (DI / 256);
    int dblk = blockIdx.x % (DI / 256);
    int d = dblk * 256 + t;

    if (t < NS) Bc[t] = x_db[(size_t)b * NJ + RK + t];
    else if (t < 2 * NS) Cc[t - NS] = x_db[(size_t)b * NJ + RK + t];
    __syncthreads();

    size_t off = (size_t)b * DI + d;
    float dt = dt_bd[off];
    float cv = conv_bd[off];
    float rv = res_bd[off];
    float Dd = Dv[d];

    const f32x4* ap = (const f32x4*)(A_log + (size_t)d * NS);
    const f32x4* sp = (const f32x4*)(ssm_state + off * NS);

    float y = 0.f;
    #pragma unroll
    for (int q = 0; q < 4; ++q) {
        f32x4 al = ap[q];
        f32x4 sv = sp[q];
        #pragma unroll
        for (int j = 0; j < 4; ++j) {
            int n = q * 4 + j;
            float dA = __expf(-dt * __expf(al[j]));
            y += (sv[j] * dA + dt * Bc[n] * cv) * Cc[n];
        }
    }
    y += Dd * cv;
    g_bd[off] = y * (rv * sigmoidf_(rv));
}

// ---------------------------------------------------------------------------

extern "C" void kernel_launch(void* const* d_in, const int* in_sizes, int n_in,
                              void* d_out, int out_size, void* d_ws, size_t ws_size,
                              hipStream_t stream)
{
    const float* x           = (const float*)d_in[0];
    const float* conv_states = (const float*)d_in[1];
    const float* conv_w      = (const float*)d_in[2];
    const float* conv_b      = (const float*)d_in[3];
    const float* W_ssm_in    = (const float*)d_in[4];
    const float* W_mlp       = (const float*)d_in[5];
    const float* W_out       = (const float*)d_in[6];
    const float* W_x_proj    = (const float*)d_in[7];
    const float* W_dt        = (const float*)d_in[8];
    const float* dt_bias     = (const float*)d_in[9];
    const float* A_log       = (const float*)d_in[10];
    const float* Dv          = (const float*)d_in[11];
    const float* ssm_state   = (const float*)d_in[12];

    float* out = (float*)d_out;
    float* ws  = (float*)d_ws;

    const size_t BD = (size_t)BB * DI;          // 163840
    const int S1 = 4;                           // K1 split-K
    const int S2 = 20;                          // K2 split-K
    const int S4 = 8;                           // K4 split-K

    float* P_res   = ws;                        // S1*BD
    float* P_xs    = ws + S1 * BD;              // S1*BD
    float* conv_bd = ws + 2 * S1 * BD;
    float* res_bd  = conv_bd + BD;
    float* dt_bd   = res_bd + BD;
    float* x_db_p  = dt_bd + BD;                // S2 * 6144
    float* x_db    = x_db_p + (size_t)S2 * BB * NJ;
    float* g_bd    = P_res;                     // alias: P_res dead after convk
    float* outp    = P_xs;                      // alias: P_xs dead after convk (S4*BB*DM = 4*BD)

    // K1: res/xs partials (dual matrix): K=2560, S=4, ksteps=10
    gemm32<<<dim3(160 * S1 * 2), 256, 0, stream>>>(
        W_mlp, P_res, W_ssm_in, P_xs, x, DM, DI, 160, S1, (DM / S1) / 64, (int)BD);

    // conv + silu + reduce K1 partials
    convk<<<dim3(DI / 256, BB), 256, 0, stream>>>(
        P_xs, P_res, conv_states, conv_w, conv_b, conv_bd, res_bd);

    // K2: x_db partials = conv @ W_x_proj.T  (K=5120, S=20, ksteps=4)
    gemm32<<<dim3(6 * S2), 256, 0, stream>>>(
        W_x_proj, x_db_p, W_x_proj, x_db_p, conv_bd, DI, NJ, 6, S2, (DI / S2) / 64, BB * NJ);

    // reduce x_db partials
    redx<<<dim3((BB * NJ) / 256), 256, 0, stream>>>(x_db_p, x_db, S2);

    // dt GEMV + softplus
    dtk<<<dim3(DI / 8), 256, 0, stream>>>(x_db, W_dt, dt_bias, dt_bd);

    // SSM recurrence + gate
    ssm2<<<dim3(BB * (DI / 256)), 256, 0, stream>>>(
        x_db, dt_bd, A_log, Dv, ssm_state, conv_bd, res_bd, g_bd);

    // K4: out partials = g @ W_out.T  (K=5120, S=8, ksteps=10)
    gemm32<<<dim3(80 * S4), 256, 0, stream>>>(
        W_out, outp, W_out, outp, g_bd, DI, DM, 80, S4, (DI / S4) / 64, BB * DM);

    // final reduce into d_out
    rout<<<dim3((BB * DM) / 256), 256, 0, stream>>>(outp, out);
}